// Round 3
// baseline (198.047 us; speedup 1.0000x reference)
//
#include <hip/hip_runtime.h>

#define NF   16
#define C    8
#define NB   4
#define NPIX (512*512)
#define CHUNKS 32
#define CHUNK (NPIX / CHUNKS)   // 8192 pixels per sums block

// ws float layout:
//   [0,512)     sums[b][c*16+f]
//   [512,544)   counts[b*8+c]
//   [544,1056)  means[b][f*8+c]   (transposed for conflict-free LDS gather)
//   [1056,1060) invsum[b]
#define WS_CNT   512
#define WS_MEAN  544
#define WS_INV   1056
#define WS_TOTAL 1060

__global__ void init_kernel(float* __restrict__ ws, float* __restrict__ out) {
    int t = blockIdx.x * blockDim.x + threadIdx.x;
    if (t < WS_TOTAL) ws[t] = 0.0f;
    if (t == 0) out[0] = 0.0f;
}

// One feature row per block: contiguous streaming (no 1MB-stride multi-stream).
// grid = (CHUNKS, NF, NB) = 2048 blocks -> 8192 waves (full grid occupancy).
__global__ __launch_bounds__(256) void sums_kernel(const float* __restrict__ pred,
                                                   const int* __restrict__ tgt,
                                                   float* __restrict__ ws) {
    const int tid = threadIdx.x;
    const int f   = blockIdx.y;
    const int b   = blockIdx.z;
    const int start = blockIdx.x * CHUNK;
    const float* pf   = pred + ((size_t)b * NF + f) * NPIX;
    const int*   tgtb = tgt  + (size_t)b * NPIX;
    const bool do_cnt = (f == 0);

    float acc[8], cnt[8];
#pragma unroll
    for (int c = 0; c < 8; ++c) { acc[c] = 0.0f; cnt[c] = 0.0f; }

    // 8 pixels/thread/iter (2x float4), 4 iterations
    for (int base = start + tid * 8; base < start + CHUNK; base += 256 * 8) {
        int4   la = *(const int4*)(tgtb + base);
        int4   lb = *(const int4*)(tgtb + base + 4);
        float4 pa = *(const float4*)(pf + base);
        float4 pb = *(const float4*)(pf + base + 4);
#pragma unroll
        for (int c = 0; c < 8; ++c) {
            acc[c] += (la.x == c ? pa.x : 0.0f) + (la.y == c ? pa.y : 0.0f)
                    + (la.z == c ? pa.z : 0.0f) + (la.w == c ? pa.w : 0.0f)
                    + (lb.x == c ? pb.x : 0.0f) + (lb.y == c ? pb.y : 0.0f)
                    + (lb.z == c ? pb.z : 0.0f) + (lb.w == c ? pb.w : 0.0f);
        }
        if (do_cnt) {
#pragma unroll
            for (int c = 0; c < 8; ++c) {
                cnt[c] += (la.x == c ? 1.0f : 0.0f) + (la.y == c ? 1.0f : 0.0f)
                        + (la.z == c ? 1.0f : 0.0f) + (la.w == c ? 1.0f : 0.0f)
                        + (lb.x == c ? 1.0f : 0.0f) + (lb.y == c ? 1.0f : 0.0f)
                        + (lb.z == c ? 1.0f : 0.0f) + (lb.w == c ? 1.0f : 0.0f);
            }
        }
    }

    // within-wave butterfly; each wave commits its own atomics (4 waves/block)
#pragma unroll
    for (int off = 32; off > 0; off >>= 1)
#pragma unroll
        for (int c = 0; c < 8; ++c) acc[c] += __shfl_down(acc[c], off);
    if (do_cnt) {
#pragma unroll
        for (int off = 32; off > 0; off >>= 1)
#pragma unroll
            for (int c = 0; c < 8; ++c) cnt[c] += __shfl_down(cnt[c], off);
    }

    if ((tid & 63) == 0) {
        float* gsum = ws + b * (C * NF);
#pragma unroll
        for (int c = 0; c < 8; ++c) atomicAdd(&gsum[c * NF + f], acc[c]);
        if (do_cnt) {
            float* gcnt = ws + WS_CNT + b * C;
#pragma unroll
            for (int c = 0; c < 8; ++c) atomicAdd(&gcnt[c], cnt[c]);
        }
    }
}

__global__ void means_kernel(float* __restrict__ ws) {
    int t = threadIdx.x;               // 512 threads: b=t/128, c=(t/16)%8, f=t%16
    int b = t >> 7;
    int r = t & 127;
    int c = r >> 4;
    int f = r & 15;
    float cnt = ws[WS_CNT + b * C + c];
    ws[WS_MEAN + b * 128 + f * C + c] = ws[b * 128 + c * NF + f] / cnt;
    if (f == 0) atomicAdd(&ws[WS_INV + b], 1.0f / cnt);
}

// All 17 loads hoisted into registers before consumption -> max memory-level
// parallelism per wave (17KB in flight) to ride out queued HBM latency.
__global__ __launch_bounds__(256) void dist_kernel(const float* __restrict__ pred,
                                                   const int* __restrict__ tgt,
                                                   const float* __restrict__ ws,
                                                   float* __restrict__ out) {
    __shared__ float s_means[C * NF];
    __shared__ float s_red[4];
    const int tid = threadIdx.x;
    const int b   = blockIdx.y;
    if (tid < C * NF) s_means[tid] = ws[WS_MEAN + b * 128 + tid];
    const float invs = ws[WS_INV + b];
    __syncthreads();

    const float* predb = pred + (size_t)b * NF * NPIX;
    const int*   tgtb  = tgt  + (size_t)b * NPIX;
    const int base = (blockIdx.x * 256 + tid) * 4;   // one-shot: 256 blocks/batch

    int4 lab = *(const int4*)(tgtb + base);
    float4 p[NF];
#pragma unroll
    for (int f = 0; f < NF; ++f) p[f] = *(const float4*)(predb + f * NPIX + base);

    float s0 = 0.f, s1 = 0.f, s2 = 0.f, s3 = 0.f;
#pragma unroll
    for (int f = 0; f < NF; ++f) {
        float d0 = s_means[f * C + lab.x] - p[f].x;
        float d1 = s_means[f * C + lab.y] - p[f].y;
        float d2 = s_means[f * C + lab.z] - p[f].z;
        float d3 = s_means[f * C + lab.w] - p[f].w;
        s0 += d0 * d0; s1 += d1 * d1; s2 += d2 * d2; s3 += d3 * d3;
    }
    float t0 = fminf(fmaxf(sqrtf(s0) - 0.5f, 0.0f), 100000.0f);
    float t1 = fminf(fmaxf(sqrtf(s1) - 0.5f, 0.0f), 100000.0f);
    float t2 = fminf(fmaxf(sqrtf(s2) - 0.5f, 0.0f), 100000.0f);
    float t3 = fminf(fmaxf(sqrtf(s3) - 0.5f, 0.0f), 100000.0f);
    float acc = t0 * t0 + t1 * t1 + t2 * t2 + t3 * t3;

#pragma unroll
    for (int off = 32; off > 0; off >>= 1) acc += __shfl_down(acc, off);
    const int lane = tid & 63, wave = tid >> 6;
    if (lane == 0) s_red[wave] = acc;
    __syncthreads();
    if (tid == 0) {
        float tot = s_red[0] + s_red[1] + s_red[2] + s_red[3];
        atomicAdd(out, tot * invs * 0.125f);
    }
}

extern "C" void kernel_launch(void* const* d_in, const int* in_sizes, int n_in,
                              void* d_out, int out_size, void* d_ws, size_t ws_size,
                              hipStream_t stream) {
    const float* pred = (const float*)d_in[0];
    const int*   tgt  = (const int*)d_in[1];
    float* out = (float*)d_out;
    float* ws  = (float*)d_ws;

    init_kernel<<<dim3((WS_TOTAL + 255) / 256), dim3(256), 0, stream>>>(ws, out);
    sums_kernel<<<dim3(CHUNKS, NF, NB), dim3(256), 0, stream>>>(pred, tgt, ws);
    means_kernel<<<dim3(1), dim3(512), 0, stream>>>(ws);
    dist_kernel<<<dim3(256, NB), dim3(256), 0, stream>>>(pred, tgt, ws, out);
}